// Round 7
// baseline (2008.988 us; speedup 1.0000x reference)
//
#include <hip/hip_runtime.h>
#include <hip/hip_bf16.h>
#include <cstdint>
#include <cstddef>

typedef __bf16 bf16_t;
typedef __bf16 bf16x8 __attribute__((ext_vector_type(8)));
typedef float  f32x4  __attribute__((ext_vector_type(4)));

#define TOKENS 16384
#define HIDDEN 2048
#define FFN    8192

__device__ __forceinline__ void gload_lds16(const bf16_t* g, bf16_t* l) {
    __builtin_amdgcn_global_load_lds((const __attribute__((address_space(1))) void*)g,
                                     (__attribute__((address_space(3))) void*)l,
                                     16, 0, 0);
}

__global__ void cvt_f32_to_bf16(const float* __restrict__ in, bf16_t* __restrict__ out, int n8) {
    int i = blockIdx.x * blockDim.x + threadIdx.x;
    if (i >= n8) return;
    size_t base = (size_t)i * 8;
    f32x4 v0 = *(const f32x4*)&in[base];
    f32x4 v1 = *(const f32x4*)&in[base + 4];
    bf16x8 o;
    o[0] = (bf16_t)v0[0]; o[1] = (bf16_t)v0[1]; o[2] = (bf16_t)v0[2]; o[3] = (bf16_t)v0[3];
    o[4] = (bf16_t)v1[0]; o[5] = (bf16_t)v1[1]; o[6] = (bf16_t)v1[2]; o[7] = (bf16_t)v1[3];
    *(bf16x8*)&out[base] = o;
}

__global__ void transpose_cvt(const float* __restrict__ src, bf16_t* __restrict__ dst,
                              int R, int C) {
    __shared__ bf16_t tile[64][66];
    const int tcols = C >> 6;
    const int bx = blockIdx.x % tcols;
    const int by = blockIdx.x / tcols;
    const int c0 = bx << 6, r0 = by << 6;
    const int t = threadIdx.x;
#pragma unroll
    for (int i = 0; i < 16; ++i) {
        int idx = i * 256 + t;
        int rr = idx >> 6, cc = idx & 63;
        tile[rr][cc] = (bf16_t)src[(size_t)(r0 + rr) * C + (c0 + cc)];
    }
    __syncthreads();
#pragma unroll
    for (int i = 0; i < 16; ++i) {
        int idx = i * 256 + t;
        int cc = idx >> 6, rr = idx & 63;
        dst[(size_t)(c0 + cc) * R + (r0 + rr)] = tile[rr][cc];
    }
}

// ---------------------------------------------------------------------------
// 256x256 8-phase GEMM with CROSS-PHASE REGISTER PIPELINE.
// Skeleton (barriers, STAGE slots, VMW(6) ledger, swizzle) identical to the
// round-4 proven kernel. Each phase issues the NEXT cluster's ds_reads;
// counted lgkmcnt(N) (N = this phase's read count) replaces the full drain,
// so operands are a full phase old at consumption and LDS traffic overlaps
// MFMA of the current cluster.
//
// Consume/read/stage schedule per iteration (buf0 = tile t0, buf1 = t1):
//  P1: Q00(afA,bA) | rd B1(b0)->bB {4}  | stg t1.A1
//  P2: Q01(afA,bB) | rd A1(b0)->afB {8} |
//  P3: Q11(afB,bB) |                    | stg t2.B0
//  P4: Q10(afB,bA) | stg t2.B1,t2.A0; VMW(6); BAR; rd A0(b1)->afA, B0(b1)->bB {12}
//  P5: Q00(afA,bB) | rd B1(b1)->bA {4}  | stg t2.A1
//  P6: Q01(afA,bA) | rd A1(b1)->afB {8} |
//  P7: Q11(afB,bA) |                    | stg t3.B0
//  P8: Q10(afB,bB) | stg t3.B1,t3.A0; VMW(6); BAR; rd A0(b0)->afA, B0(b0)->bA {12}
// Counted-wait ledger: P1 w4 (drains P8's 12), P2 w8 (drains P1's 4),
// P3 w0 (drains P2's 8), P4 w12 (nothing older), P5 w4 (drains P4's 12),
// P6 w8, P7 w0, P8 w12. Cross-wave staging visibility: buf reads at P4/P8
// occur AFTER the barrier that follows every wave's VMW(6). LDS WAR margins
// (stage vs last read of region): all >= 3 phases with barriers between.
// vmcnt ledger unchanged from round 4 (entry 6; +2 P1; +2 P3; +4 P4;
// VMW(6) retires all prev tile; mirrored P5..P8).
// ---------------------------------------------------------------------------
#define BAR() __builtin_amdgcn_s_barrier()
#define SB0() __builtin_amdgcn_sched_barrier(0)
#define LGKMW(n) do { asm volatile("s_waitcnt lgkmcnt(" #n ")" ::: "memory"); SB0(); } while (0)
#define VMW(n) asm volatile("s_waitcnt vmcnt(" #n ")" ::: "memory")
#define PRIO1() __builtin_amdgcn_s_setprio(1)
#define PRIO0() __builtin_amdgcn_s_setprio(0)

#define DS_A(BUF, QM, AF) do { \
    _Pragma("unroll") for (int mf = 0; mf < 4; ++mf) \
    _Pragma("unroll") for (int ks = 0; ks < 2; ++ks) \
        AF[mf][ks] = *(const bf16x8*)&smem[(BUF)*16384 + wr*8192 + (((QM)*4+mf)*2+ks)*512 + lnb_e]; \
} while (0)

#define DS_Bm(BUF, QN, BB) do { \
    _Pragma("unroll") for (int nf = 0; nf < 2; ++nf) \
    _Pragma("unroll") for (int ks = 0; ks < 2; ++ks) \
        BB[nf][ks] = *(const bf16x8*)&smem[32768 + (BUF)*16384 + bhalf + (((QN)*2+nf)*2+ks)*512 + lnb_e]; \
} while (0)

#define MFMA_Q(QM, QN, AF, BB) do { \
    _Pragma("unroll") for (int ks = 0; ks < 2; ++ks) \
    _Pragma("unroll") for (int mf = 0; mf < 4; ++mf) \
    _Pragma("unroll") for (int nf = 0; nf < 2; ++nf) \
        acc[(QM)*4+mf][(QN)*2+nf] = __builtin_amdgcn_mfma_f32_16x16x32_bf16( \
            AF[mf][ks], BB[nf][ks], acc[(QM)*4+mf][(QN)*2+nf], 0, 0, 0); \
} while (0)

#define STAGE(GBASE, HROWS, TILE, EOFF) do { \
    gload_lds16((GBASE) + aoff0 + (size_t)(HROWS) * K + (TILE) * 64, \
                &smem[(EOFF) + wave * 512]); \
    gload_lds16((GBASE) + aoff1 + (size_t)(HROWS) * K + (TILE) * 64, \
                &smem[(EOFF) + 4096 + wave * 512]); \
} while (0)

template<bool GELU_EPI, int M, int N, int K>
__global__ __launch_bounds__(512, 2)
void gemmpl(const bf16_t* __restrict__ A, const bf16_t* __restrict__ BT,
            const float* __restrict__ bias, void* __restrict__ out)
{
    constexpr int BM = 256, BN = 256;
    constexpr int NT = K / 64, NI = NT / 2;
    constexpr int NBN = N / BN;
    __shared__ __align__(128) bf16_t smem[65536];   // 128 KiB

    const int t = threadIdx.x;
    const int wave = t >> 6, lane = t & 63;
    const int fr = lane & 15, fq = lane >> 4;
    const int wr = wave >> 2, wc = wave & 3;

    int wg = blockIdx.x;
    { const int cpx = (int)gridDim.x >> 3; wg = (wg & 7) * cpx + (wg >> 3); }
    const int bm = wg / NBN, bn = wg % NBN;
    const int rowA0 = bm * BM, colB0 = bn * BN;

    // staging source pre-swizzle (inverse st_16x32), proven rounds 4-6
    int sr0, sk0, sr1, sk1;
    {
        int o = t * 16;
        int ri = (o >> 6) & 15;
        int b = (o & 63) ^ ((ri & 8) << 2);
        sr0 = ((o >> 10) >> 1) * 16 + ri;
        sk0 = ((o >> 10) & 1) * 32 + (b >> 1);
        o = 8192 + t * 16;
        ri = (o >> 6) & 15;
        b = (o & 63) ^ ((ri & 8) << 2);
        sr1 = ((o >> 10) >> 1) * 16 + ri;
        sk1 = ((o >> 10) & 1) * 32 + (b >> 1);
    }
    const bf16_t* gA0 = A + (size_t)rowA0 * K;
    const bf16_t* gB0 = BT + (size_t)colB0 * K;
    const size_t aoff0 = (size_t)sr0 * K + sk0;
    const size_t aoff1 = (size_t)sr1 * K + sk1;

    const int lnb_e = fr * 32 + ((fq * 8) ^ ((fr & 8) << 1));
    const int bhalf = (wc >> 1) * 8192 + (wc & 1) * 4096;

    f32x4 acc[8][4] = {};
    bf16x8 afA[4][2], afB[4][2], bA[2][2], bB[2][2];

    // prologue: stage t0 fully + t1.A0/B0/B1; drain t0; preload P1 operands
    STAGE(gA0, 0,   0, 0);          // t0.A0
    STAGE(gA0, 128, 0, 8192);       // t0.A1
    STAGE(gB0, 0,   0, 32768);      // t0.B0
    STAGE(gB0, 128, 0, 40960);      // t0.B1
    STAGE(gA0, 0,   1, 16384);      // t1.A0
    STAGE(gB0, 0,   1, 49152);      // t1.B0
    STAGE(gB0, 128, 1, 57344);      // t1.B1
    VMW(6);                         // t0 landed (6 = t1's loads in flight)
    BAR();
    DS_A(0, 0, afA); DS_Bm(0, 0, bA);   // 12 reads for P1's Q00

    for (int i = 0; i < NI - 1; ++i) {
        const int t1 = 2 * i + 1, t2 = 2 * i + 2, t3 = 2 * i + 3;
        // P1
        DS_Bm(0, 1, bB);
        STAGE(gA0, 128, t1, 24576);            // buf1.A1 <- t1.A1
        BAR(); LGKMW(4);
        PRIO1(); MFMA_Q(0, 0, afA, bA); PRIO0();
        BAR();
        // P2
        DS_A(0, 1, afB);
        BAR(); LGKMW(8);
        PRIO1(); MFMA_Q(0, 1, afA, bB); PRIO0();
        BAR();
        // P3
        STAGE(gB0, 0, t2, 32768);              // buf0.B0 <- t2.B0
        BAR(); LGKMW(0);
        PRIO1(); MFMA_Q(1, 1, afB, bB); PRIO0();
        BAR();
        // P4
        STAGE(gB0, 128, t2, 40960);            // buf0.B1 <- t2.B1
        STAGE(gA0, 0,   t2, 0);                // buf0.A0 <- t2.A0
        VMW(6);                                // all t1 landed (this wave)
        BAR();                                 // -> all waves' t1 visible
        DS_A(1, 0, afA); DS_Bm(1, 0, bB);      // 12 reads for P5's Q00
        LGKMW(12);
        PRIO1(); MFMA_Q(1, 0, afB, bA); PRIO0();
        BAR();
        // P5
        DS_Bm(1, 1, bA);
        STAGE(gA0, 128, t2, 8192);             // buf0.A1 <- t2.A1
        BAR(); LGKMW(4);
        PRIO1(); MFMA_Q(0, 0, afA, bB); PRIO0();
        BAR();
        // P6
        DS_A(1, 1, afB);
        BAR(); LGKMW(8);
        PRIO1(); MFMA_Q(0, 1, afA, bA); PRIO0();
        BAR();
        // P7
        STAGE(gB0, 0, t3, 49152);              // buf1.B0 <- t3.B0
        BAR(); LGKMW(0);
        PRIO1(); MFMA_Q(1, 1, afB, bA); PRIO0();
        BAR();
        // P8
        STAGE(gB0, 128, t3, 57344);            // buf1.B1 <- t3.B1
        STAGE(gA0, 0,   t3, 16384);            // buf1.A0 <- t3.A0
        VMW(6);                                // all t2 landed
        BAR();
        DS_A(0, 0, afA); DS_Bm(0, 0, bA);      // 12 reads for next P1's Q00
        LGKMW(12);
        PRIO1(); MFMA_Q(1, 0, afB, bB); PRIO0();
        BAR();
    }

    // peeled last iteration: tiles NT-2 (buf0), NT-1 (buf1)
    // P1p
    DS_Bm(0, 1, bB);
    STAGE(gA0, 128, NT - 1, 24576);            // buf1.A1 <- last tile A1
    BAR(); LGKMW(4);
    PRIO1(); MFMA_Q(0, 0, afA, bA); PRIO0();
    BAR();
    // P2p
    DS_A(0, 1, afB);
    BAR(); LGKMW(8);
    PRIO1(); MFMA_Q(0, 1, afA, bB); PRIO0();
    BAR();
    // P3p
    BAR(); LGKMW(0);
    PRIO1(); MFMA_Q(1, 1, afB, bB); PRIO0();
    BAR();
    // P4p
    VMW(0);                                    // final tile fully landed
    BAR();
    DS_A(1, 0, afA); DS_Bm(1, 0, bB);
    LGKMW(12);
    PRIO1(); MFMA_Q(1, 0, afB, bA); PRIO0();
    BAR();
    // P5p
    DS_Bm(1, 1, bA);
    BAR(); LGKMW(4);
    PRIO1(); MFMA_Q(0, 0, afA, bB); PRIO0();
    BAR();
    // P6p
    DS_A(1, 1, afB);
    BAR(); LGKMW(8);
    PRIO1(); MFMA_Q(0, 1, afA, bA); PRIO0();
    BAR();
    // P7p
    BAR(); LGKMW(0);
    PRIO1(); MFMA_Q(1, 1, afB, bA); PRIO0();
    BAR();
    // P8p
    LGKMW(0);
    PRIO1(); MFMA_Q(1, 0, afB, bB); PRIO0();

    // epilogue: C/D layout col=lane&15, row=(lane>>4)*4+reg
    const int orow = rowA0 + wr * 128 + fq * 4;
    const int ocol = colB0 + wc * 64 + fr;
#pragma unroll
    for (int mf = 0; mf < 8; ++mf) {
#pragma unroll
        for (int nf = 0; nf < 4; ++nf) {
            const int c = ocol + nf * 16;
            const float bv = bias[c];
#pragma unroll
            for (int v = 0; v < 4; ++v) {
                const int r = orow + mf * 16 + v;
                float xv = acc[mf][nf][v] + bv;
                if constexpr (GELU_EPI) {
                    float g = 0.5f * xv * (1.0f + erff(xv * 0.70710678118654752f));
                    ((bf16_t*)out)[(size_t)r * N + c] = (bf16_t)g;
                } else {
                    ((float*)out)[(size_t)r * N + c] = xv;
                }
            }
        }
    }
}

extern "C" void kernel_launch(void* const* d_in, const int* in_sizes, int n_in,
                              void* d_out, int out_size, void* d_ws, size_t ws_size,
                              hipStream_t stream) {
    const float* x  = (const float*)d_in[0];
    const float* w1 = (const float*)d_in[1];
    const float* b1 = (const float*)d_in[2];
    const float* w2 = (const float*)d_in[3];
    const float* b2 = (const float*)d_in[4];
    float* y = (float*)d_out;

    const size_t xb_elems  = (size_t)TOKENS * HIDDEN;
    const size_t w1t_elems = (size_t)FFN * HIDDEN;
    const size_t w2t_elems = (size_t)HIDDEN * FFN;
    const size_t h_elems   = (size_t)TOKENS * FFN;
    const size_t need = (xb_elems + w1t_elems + w2t_elems + h_elems) * sizeof(bf16_t);
    if (ws_size < need) return;

    char* ws = (char*)d_ws;
    bf16_t* xb  = (bf16_t*)ws;
    bf16_t* w1t = xb + xb_elems;
    bf16_t* w2t = w1t + w1t_elems;
    bf16_t* h   = w2t + w2t_elems;

    cvt_f32_to_bf16<<<(TOKENS * HIDDEN / 8 + 255) / 256, 256, 0, stream>>>(
        x, xb, TOKENS * HIDDEN / 8);
    transpose_cvt<<<(HIDDEN / 64) * (FFN / 64), 256, 0, stream>>>(w1, w1t, HIDDEN, FFN);
    transpose_cvt<<<(FFN / 64) * (HIDDEN / 64), 256, 0, stream>>>(w2, w2t, FFN, HIDDEN);

    gemmpl<true, TOKENS, FFN, HIDDEN>
        <<<(TOKENS / 256) * (FFN / 256), 512, 0, stream>>>(xb, w1t, b1, h);
    gemmpl<false, TOKENS, HIDDEN, FFN>
        <<<(TOKENS / 256) * (HIDDEN / 256), 512, 0, stream>>>(h, w2t, b2, y);
}